// Round 15
// baseline (838.533 us; speedup 1.0000x reference)
//
#include <hip/hip_runtime.h>
#include <hip/hip_bf16.h>

#define N_NODES 32768
#define F_IN    32
#define HC      64
#define HEADS   4
#define NE      524288
#define NET     (NE + N_NODES)   /* 557056 = 2176*256 */
#define NG      64
#define TT      512
#define OUTF    24

__device__ __forceinline__ float lrelu(float x){ return x > 0.f ? x : 0.2f*x; }
__device__ __forceinline__ float eluf (float x){ return x > 0.f ? x : __expf(x)-1.f; }
__device__ __forceinline__ float sigmf(float x){ return 1.f/(1.f+__expf(-x)); }
__device__ __forceinline__ float tanhfast(float x){ return 1.f - 2.f/(__expf(2.f*x)+1.f); }
__device__ __forceinline__ float bcast(float v, int k){
  return __int_as_float(__builtin_amdgcn_readlane(__float_as_int(v), k));
}

// ---------------- CSR build: incoming-edge lists per destination ----------------
__global__ __launch_bounds__(256) void k_deg(const int* __restrict__ ei,
                                             int* __restrict__ deg){
  int e = blockIdx.x*256 + threadIdx.x;   // e < NET
  int d = (e < NE) ? ei[NE+e] : (e - NE);
  atomicAdd(deg + d, 1);
}

__global__ __launch_bounds__(1024) void k_scan(const int* __restrict__ deg,
                                               int* __restrict__ rowptr){
  __shared__ int ps[1024];
  const int t = threadIdx.x;
  const int base = t*32;
  int local[32]; int s = 0;
  #pragma unroll
  for(int i=0;i<32;i++){ local[i]=deg[base+i]; s+=local[i]; }
  ps[t]=s; __syncthreads();
  for(int off=1; off<1024; off<<=1){
    int v = (t>=off) ? ps[t-off] : 0;
    __syncthreads();
    ps[t]+=v;
    __syncthreads();
  }
  int run = (t==0) ? 0 : ps[t-1];
  #pragma unroll
  for(int i=0;i<32;i++){ rowptr[base+i]=run; run+=local[i]; }
  if(t==1023) rowptr[N_NODES]=run;
}

__global__ __launch_bounds__(256) void k_fill(const int* __restrict__ ei,
                                              const int* __restrict__ rowptr,
                                              int* __restrict__ cur,
                                              int* __restrict__ col){
  int e = blockIdx.x*256 + threadIdx.x;   // e < NET
  int s, d;
  if(e < NE){ s = ei[e]; d = ei[NE+e]; } else { s = e-NE; d = s; }
  int pos = atomicAdd(cur + d, 1);
  col[rowptr[d] + pos] = s;
}

// ---------------- GAT layer 1, restructured (h1 never materialized) ----------------
__global__ __launch_bounds__(256) void k_alpha1x(const float* __restrict__ x,
                                                 const float* __restrict__ W1,
                                                 const float* __restrict__ a_src,
                                                 const float* __restrict__ a_dst,
                                                 float* __restrict__ as1,
                                                 float* __restrict__ ad1){
  __shared__ float ps[256];
  const int tid = threadIdx.x;
  {
    const int k = tid>>3, q = tid&7;
    const int h = q>>1, isd = q&1;
    const float* av = (isd ? a_dst : a_src) + h*64;
    const float* wr = W1 + k*256 + h*64;
    float acc = 0.f;
    #pragma unroll
    for(int c=0;c<64;c++) acc += wr[c]*av[c];
    ps[(isd?128:0) + k*4 + h] = acc;
  }
  __syncthreads();
  const int n = blockIdx.x*256 + tid;
  const float4* xr = (const float4*)(x + n*32);
  float sa0=0.f,sa1=0.f,sa2=0.f,sa3=0.f, sd0=0.f,sd1=0.f,sd2=0.f,sd3=0.f;
  #pragma unroll
  for(int k4=0;k4<8;k4++){
    float4 v = xr[k4];
    const float* pa = ps + (4*k4)*4;
    const float* pd = ps + 128 + (4*k4)*4;
    sa0 += v.x*pa[0] + v.y*pa[4] + v.z*pa[8]  + v.w*pa[12];
    sa1 += v.x*pa[1] + v.y*pa[5] + v.z*pa[9]  + v.w*pa[13];
    sa2 += v.x*pa[2] + v.y*pa[6] + v.z*pa[10] + v.w*pa[14];
    sa3 += v.x*pa[3] + v.y*pa[7] + v.z*pa[11] + v.w*pa[15];
    sd0 += v.x*pd[0] + v.y*pd[4] + v.z*pd[8]  + v.w*pd[12];
    sd1 += v.x*pd[1] + v.y*pd[5] + v.z*pd[9]  + v.w*pd[13];
    sd2 += v.x*pd[2] + v.y*pd[6] + v.z*pd[10] + v.w*pd[14];
    sd3 += v.x*pd[3] + v.y*pd[7] + v.z*pd[11] + v.w*pd[15];
  }
  *(float4*)(as1+n*4) = make_float4(sa0,sa1,sa2,sa3);
  *(float4*)(ad1+n*4) = make_float4(sd0,sd1,sd2,sd3);
}

// aggregate x per (node, head): agg[d,h,k] = sum_e w_e^h x[src_e,k]; s14 = sum w.
__global__ __launch_bounds__(256) void k_gatx(const int* __restrict__ rowptr,
                                              const int* __restrict__ col,
                                              const float* __restrict__ as1,
                                              const float* __restrict__ ad1,
                                              const float* __restrict__ x,
                                              float* __restrict__ agg,
                                              float* __restrict__ s14){
  const int node = blockIdx.x*4 + (threadIdx.x>>6);
  const int lane = threadIdx.x & 63;
  const int h0   = lane>>5;                  // 0 or 1
  const int c    = lane & 31;
  const int beg = rowptr[node], end = rowptr[node+1];
  const float adA = ad1[node*4 + h0];
  const float adB = ad1[node*4 + h0 + 2];
  float accA=0.f, accB=0.f, wsA=0.f, wsB=0.f;
  int j = beg;
  for(; j+3 < end; j += 4){
    int s0 = col[j], s1 = col[j+1], s2 = col[j+2], s3 = col[j+3];
    float4 q0 = *(const float4*)(as1 + s0*4);
    float4 q1 = *(const float4*)(as1 + s1*4);
    float4 q2 = *(const float4*)(as1 + s2*4);
    float4 q3 = *(const float4*)(as1 + s3*4);
    float x0 = x[s0*32 + c];
    float x1 = x[s1*32 + c];
    float x2 = x[s2*32 + c];
    float x3 = x[s3*32 + c];
    float wA0 = __expf(lrelu((h0?q0.y:q0.x) + adA));
    float wA1 = __expf(lrelu((h0?q1.y:q1.x) + adA));
    float wA2 = __expf(lrelu((h0?q2.y:q2.x) + adA));
    float wA3 = __expf(lrelu((h0?q3.y:q3.x) + adA));
    float wB0 = __expf(lrelu((h0?q0.w:q0.z) + adB));
    float wB1 = __expf(lrelu((h0?q1.w:q1.z) + adB));
    float wB2 = __expf(lrelu((h0?q2.w:q2.z) + adB));
    float wB3 = __expf(lrelu((h0?q3.w:q3.z) + adB));
    accA += wA0*x0 + wA1*x1 + wA2*x2 + wA3*x3;
    accB += wB0*x0 + wB1*x1 + wB2*x2 + wB3*x3;
    wsA  += (wA0+wA1) + (wA2+wA3);
    wsB  += (wB0+wB1) + (wB2+wB3);
  }
  for(; j < end; j++){
    int s0 = col[j];
    float4 q0 = *(const float4*)(as1 + s0*4);
    float wA0 = __expf(lrelu((h0?q0.y:q0.x) + adA));
    float wB0 = __expf(lrelu((h0?q0.w:q0.z) + adB));
    float x0 = x[s0*32 + c];
    accA += wA0*x0; accB += wB0*x0;
    wsA += wA0; wsB += wB0;
  }
  agg[node*128 + h0*32 + c]     = accA;
  agg[node*128 + (h0+2)*32 + c] = accB;
  if(c == 0){
    s14[node*4 + h0]     = wsA;
    s14[node*4 + h0 + 2] = wsB;
  }
}

// Fused: out1 = ELU(agg@W1/s + b1) [LDS only] ; h2 = out1@W2 ; as2/ad2 from h2.
__global__ __launch_bounds__(256) void k_g12(const float* __restrict__ agg,
                                             const float* __restrict__ W1,
                                             const float* __restrict__ s14,
                                             const float* __restrict__ b1,
                                             const float* __restrict__ W2,
                                             const float* __restrict__ a_src2,
                                             const float* __restrict__ a_dst2,
                                             float* __restrict__ h2,
                                             float* __restrict__ as2,
                                             float* __restrict__ ad2){
  __shared__ __align__(16) float ags[32*128];   // 16KB; reused as h2 tile
  __shared__ __align__(16) float o1s[32*256];   // 32KB
  __shared__ float sv[128];
  const int tid  = threadIdx.x;
  const int row0 = blockIdx.x*32;
  const float4* ag = (const float4*)(agg + (size_t)row0*128);
  float4* a4 = (float4*)ags;
  for(int i=tid;i<1024;i+=256) a4[i]=ag[i];
  if(tid<32) ((float4*)sv)[tid]=((const float4*)(s14+row0*4))[tid];
  float wc[32];
  #pragma unroll
  for(int k=0;k<32;k++) wc[k]=W1[k*256+tid];
  const float bb=b1[tid];
  __syncthreads();
  const int h = tid>>6;
  for(int r=0;r<32;r++){
    const float4* ar=(const float4*)(ags + r*128 + h*32);
    float acc=0.f;
    #pragma unroll
    for(int k4=0;k4<8;k4++){
      float4 v=ar[k4];
      acc += v.x*wc[4*k4]+v.y*wc[4*k4+1]+v.z*wc[4*k4+2]+v.w*wc[4*k4+3];
    }
    float inv = 1.f/(sv[r*4+h] + 1e-16f);
    o1s[r*256+tid] = eluf(acc*inv + bb);
  }
  __syncthreads();
  const int c0=(tid&15)*4;
  const int r0=(tid>>4)*2;
  float acc2[2][4]={};
  for(int k=0;k<256;k+=4){
    float wv[4][4];
    #pragma unroll
    for(int i=0;i<4;i++){
      float4 w=*(const float4*)(W2+(k+i)*64+c0);
      wv[i][0]=w.x; wv[i][1]=w.y; wv[i][2]=w.z; wv[i][3]=w.w;
    }
    #pragma unroll
    for(int i=0;i<2;i++){
      float4 xv=*(const float4*)(o1s+(r0+i)*256+k);
      #pragma unroll
      for(int j=0;j<4;j++)
        acc2[i][j]+=xv.x*wv[0][j]+xv.y*wv[1][j]+xv.z*wv[2][j]+xv.w*wv[3][j];
    }
  }
  float* h2s = ags;
  #pragma unroll
  for(int i=0;i<2;i++){
    float4 o = make_float4(acc2[i][0],acc2[i][1],acc2[i][2],acc2[i][3]);
    *(float4*)(h2 + (size_t)(row0+r0+i)*64 + c0) = o;
    *(float4*)(h2s + (r0+i)*64 + c0) = o;
  }
  __syncthreads();
  if(tid < 32){
    const float4* hp=(const float4*)(h2s + tid*64);
    float sa=0.f, sd=0.f;
    #pragma unroll
    for(int i=0;i<16;i++){
      float4 v=hp[i];
      float4 a=((const float4*)a_src2)[i];
      float4 d=((const float4*)a_dst2)[i];
      sa+=v.x*a.x+v.y*a.y+v.z*a.z+v.w*a.w;
      sd+=v.x*d.x+v.y*d.y+v.z*d.z+v.w*d.w;
    }
    as2[row0+tid]=sa; ad2[row0+tid]=sd;
  }
}

// fused gather layer 2: one wave per node, lane = channel; 4-wide unrolled.
__global__ __launch_bounds__(256) void k_gat2(const int* __restrict__ rowptr,
                                              const int* __restrict__ col,
                                              const float* __restrict__ as2,
                                              const float* __restrict__ ad2,
                                              const float* __restrict__ h2,
                                              const float* __restrict__ b2,
                                              float* __restrict__ out2){
  const int node = blockIdx.x*4 + (threadIdx.x>>6);
  const int lane = threadIdx.x & 63;
  const int beg = rowptr[node], end = rowptr[node+1];
  const float ad = ad2[node];
  float acc = 0.f, s = 0.f;
  int j = beg;
  for(; j+3 < end; j += 4){
    int s0 = col[j], s1 = col[j+1], s2 = col[j+2], s3 = col[j+3];
    float a0 = as2[s0], a1 = as2[s1], a2 = as2[s2], a3 = as2[s3];
    float v0 = h2[s0*64+lane], v1 = h2[s1*64+lane];
    float v2 = h2[s2*64+lane], v3 = h2[s3*64+lane];
    float w0 = __expf(lrelu(a0 + ad));
    float w1 = __expf(lrelu(a1 + ad));
    float w2 = __expf(lrelu(a2 + ad));
    float w3 = __expf(lrelu(a3 + ad));
    acc += w0*v0 + w1*v1 + w2*v2 + w3*v3;
    s += (w0+w1) + (w2+w3);
  }
  for(; j < end; j++){
    int s0 = col[j];
    float w0 = __expf(lrelu(as2[s0] + ad));
    acc += w0*h2[s0*64+lane];
    s += w0;
  }
  const float inv = 1.f/(s + 1e-16f);
  out2[node*64+lane] = eluf(acc*inv + b2[lane]);
}

// ---------------- GRU: gi1 = in @ Wih0^T + bih0   [N,64]@[64,192] ----------------
__global__ __launch_bounds__(256) void k_gemm_gi(const float* __restrict__ in,
                                                 const float* __restrict__ Wih,
                                                 const float* __restrict__ bih,
                                                 float* __restrict__ gi){
  __shared__ __align__(16) float xs[64*64];
  __shared__ float wT[64*192];
  const int tid=threadIdx.x;
  const int row0=blockIdx.x*64;
  const float4* xg=(const float4*)(in+row0*64);
  float4* xs4=(float4*)xs;
  for(int i=tid;i<1024;i+=256) xs4[i]=xg[i];
  for(int i=tid;i<12288;i+=256){ wT[(i&63)*192+(i>>6)] = Wih[i]; }
  __syncthreads();
  if(tid<192){
    float wr[64];
    #pragma unroll
    for(int k=0;k<64;k++) wr[k]=wT[k*192+tid];
    const float bj=bih[tid];
    for(int r=0;r<64;r++){
      float acc=bj;
      const float4* xr=(const float4*)(xs+r*64);
      #pragma unroll
      for(int k4=0;k4<16;k4++){
        float4 v=xr[k4];
        acc+=v.x*wr[4*k4]+v.y*wr[4*k4+1]+v.z*wr[4*k4+2]+v.w*wr[4*k4+3];
      }
      gi[(row0+r)*192+tid]=acc;
    }
  }
}

// Fused 2-layer GRU, ONE barrier per step (vs r8's two + idle phase-B).
// Every wave redundantly advances its own hidden state in registers (6 LDS
// reads + gates per lane), then does the r8 readlane matvec on the register —
// no h LDS array, no dedicated gate phase. Races removed by parity
// double-buffers (gh1p/gi2p/gh2p: write i&1, read (i-1)&1) and a 3-slot gi1
// ring (write (i+1)%3, read (i-1)%3 — never aliases). 514 iterations.
// Skew: h1^(i)=gate(gi1[i-1],gh1^(i-1),h1^(i-1)) at iters 1..TT;
//       h2 updates at iters 2..TT+1 consuming gi2/gh2 written one iter earlier.
__global__ __launch_bounds__(576,3) void k_gru1b(const float* __restrict__ gi1,
                                                 const float* __restrict__ Whh0,
                                                 const float* __restrict__ bhh0,
                                                 const float* __restrict__ Wih1,
                                                 const float* __restrict__ bih1,
                                                 const float* __restrict__ Whh1,
                                                 const float* __restrict__ bhh1,
                                                 const float* __restrict__ Wl,
                                                 const float* __restrict__ bl,
                                                 float* __restrict__ fout){
  __shared__ float gh1p[2][192];
  __shared__ float gi2p[2][192];
  __shared__ float gh2p[2][192];
  __shared__ float g1r[3][192];
  __shared__ float h2fin[64];
  const int tid  = threadIdx.x;
  const int w    = tid >> 6;
  const int lane = tid & 63;
  const int b    = blockIdx.x;
  const float* gib = gi1 + (size_t)b*TT*192;

  const int crew = w/3;                     // 0: gh1(Whh0), 1: gi2(Wih1), 2: gh2(Whh1)
  const int row  = (w%3)*64 + lane;
  const float* W  = (crew==0) ? Whh0 : (crew==1) ? Wih1 : Whh1;
  const float* bb = (crew==0) ? bhh0 : (crew==1) ? bih1 : bhh1;

  const float4* wp = (const float4*)(W + row*64);
  float4 Wv0=wp[0],  Wv1=wp[1],  Wv2=wp[2],  Wv3=wp[3];
  float4 Wv4=wp[4],  Wv5=wp[5],  Wv6=wp[6],  Wv7=wp[7];
  float4 Wv8=wp[8],  Wv9=wp[9],  WvA=wp[10], WvB=wp[11];
  float4 WvC=wp[12], WvD=wp[13], WvE=wp[14], WvF=wp[15];
  const float bias = bb[row];

  float giv = 0.f;
  if(w < 3){                                // ring prefill: gi1[0] -> slot 0; giv = gi1[1]
    g1r[0][row] = gib[row];
    giv = gib[192 + row];
  }
  float hreg = 0.f;                         // h1 for crews 0/1, h2 for crew 2
  __syncthreads();

  for(int i=0;i<=TT+1;i++){
    const int pr = (i-1)&1;
    // ---- step 1: advance own hidden state (redundant per wave, registers only)
    if(crew < 2){
      if(i >= 1 && i <= TT){
        const int sr = (i-1)%3;
        float r = sigmf(g1r[sr][lane]     + gh1p[pr][lane]);
        float z = sigmf(g1r[sr][64+lane]  + gh1p[pr][64+lane]);
        float n = tanhfast(g1r[sr][128+lane] + r*gh1p[pr][128+lane]);
        hreg = (1.f-z)*n + z*hreg;
      }
    } else {
      if(i >= 2){
        float r = sigmf(gi2p[pr][lane]     + gh2p[pr][lane]);
        float z = sigmf(gi2p[pr][64+lane]  + gh2p[pr][64+lane]);
        float n = tanhfast(gi2p[pr][128+lane] + r*gh2p[pr][128+lane]);
        hreg = (1.f-z)*n + z*hreg;
      }
    }
    // ---- step 2: gi1 ring staging (crew-0 waves), 2 iterations ahead
    if(w < 3){
      if(i+1 <= TT-1) g1r[(i+1)%3][row] = giv;
      if(i+2 <= TT-1) giv = gib[(size_t)(i+2)*192 + row];
    }
    // ---- step 3: matvec via readlane broadcast of hreg (r8 codegen)
    if(i <= TT){
      float a0=bias, a1=0.f, a2=0.f, a3=0.f;
#define DOT4(WV, BASE) \
      a0 = fmaf(bcast(hreg, BASE+0), WV.x, a0); \
      a1 = fmaf(bcast(hreg, BASE+1), WV.y, a1); \
      a2 = fmaf(bcast(hreg, BASE+2), WV.z, a2); \
      a3 = fmaf(bcast(hreg, BASE+3), WV.w, a3);
      DOT4(Wv0, 0)  DOT4(Wv1, 4)  DOT4(Wv2, 8)  DOT4(Wv3, 12)
      DOT4(Wv4, 16) DOT4(Wv5, 20) DOT4(Wv6, 24) DOT4(Wv7, 28)
      DOT4(Wv8, 32) DOT4(Wv9, 36) DOT4(WvA, 40) DOT4(WvB, 44)
      DOT4(WvC, 48) DOT4(WvD, 52) DOT4(WvE, 56) DOT4(WvF, 60)
#undef DOT4
      float* dstp = (crew==0) ? gh1p[i&1] : (crew==1) ? gi2p[i&1] : gh2p[i&1];
      dstp[row] = (a0+a1)+(a2+a3);
    }
    __syncthreads();
  }

  if(w == 6) h2fin[lane] = hreg;            // crew-2 waves all hold h2^(TT)
  __syncthreads();
  if(tid < 24){
    float acc = bl[tid];
    const float4* wl4 = (const float4*)(Wl + tid*64);
    #pragma unroll
    for(int k4=0;k4<16;k4++){
      float4 h4 = *(const float4*)(h2fin + 4*k4);
      float4 w4 = wl4[k4];
      acc += h4.x*w4.x + h4.y*w4.y + h4.z*w4.z + h4.w*w4.w;
    }
    fout[b*24+tid] = acc;
  }
}

extern "C" void kernel_launch(void* const* d_in, const int* in_sizes, int n_in,
                              void* d_out, int out_size, void* d_ws, size_t ws_size,
                              hipStream_t stream){
  const float* x     =(const float*)d_in[0];
  const int*   ei    =(const int*  )d_in[1];
  const float* W1    =(const float*)d_in[3];
  const float* a_src1=(const float*)d_in[4];
  const float* a_dst1=(const float*)d_in[5];
  const float* b1    =(const float*)d_in[6];
  const float* W2    =(const float*)d_in[7];
  const float* a_src2=(const float*)d_in[8];
  const float* a_dst2=(const float*)d_in[9];
  const float* b2    =(const float*)d_in[10];
  const float* Wih0  =(const float*)d_in[11];
  const float* Whh0  =(const float*)d_in[12];
  const float* bih0  =(const float*)d_in[13];
  const float* bhh0  =(const float*)d_in[14];
  const float* Wih1  =(const float*)d_in[15];
  const float* Whh1  =(const float*)d_in[16];
  const float* bih1  =(const float*)d_in[17];
  const float* bhh1  =(const float*)d_in[18];
  const float* Wl    =(const float*)d_in[19];
  const float* bl    =(const float*)d_in[20];

  float* ws   = (float*)d_ws;
  float* agg  = ws;                  // 4194304 [N,128] (dead after k_g12)
  float* s14  = ws + 4194304;        // 131072 [N,4]
  float* gi   = ws;                  // overwrites agg after it's dead
  float* out2 = ws + 8388608;        // 2097152 (k_gat2 output)
  float* h2   = ws + 16777216;       // 2097152
  float* as1  = ws + 18874368;       // 131072
  float* ad1  = as1 + 131072;        // 131072
  float* as2  = ad1 + 131072;        // 32768
  float* ad2  = as2 + 32768;         // 32768
  int* rowptr = (int*)(ad2 + 32768); // 32769 (padded to 32800)
  int* deg    = rowptr + 32800;      // 32768
  int* cur    = deg + 32768;         // 32768 (contiguous with deg: one memset)
  int* col    = cur + 32768;         // 557056
  float* fo   = (float*)d_out;

  hipMemsetAsync(deg, 0, 2*32768*sizeof(int), stream);  // deg + cur

  k_deg   <<<2176,256,0,stream>>>(ei,deg);
  k_scan  <<<1  ,1024,0,stream>>>(deg,rowptr);
  k_fill  <<<2176,256,0,stream>>>(ei,rowptr,cur,col);

  k_alpha1x<<<128 ,256,0,stream>>>(x,W1,a_src1,a_dst1,as1,ad1);
  k_gatx   <<<8192,256,0,stream>>>(rowptr,col,as1,ad1,x,agg,s14);
  k_g12    <<<1024,256,0,stream>>>(agg,W1,s14,b1,W2,a_src2,a_dst2,h2,as2,ad2);
  k_gat2   <<<8192,256,0,stream>>>(rowptr,col,as2,ad2,h2,b2,out2);
  k_gemm_gi<<<512 ,256,0,stream>>>(out2,Wih0,bih0,gi);
  k_gru1b  <<<64  ,576,0,stream>>>(gi,Whh0,bhh0,Wih1,bih1,Whh1,bhh1,Wl,bl,fo);
  (void)in_sizes; (void)n_in; (void)out_size; (void)ws_size;
}

// Round 16
// 754.425 us; speedup vs baseline: 1.1115x; 1.1115x over previous
//
#include <hip/hip_runtime.h>
#include <hip/hip_bf16.h>

#define N_NODES 32768
#define F_IN    32
#define HC      64
#define HEADS   4
#define NE      524288
#define NET     (NE + N_NODES)   /* 557056 = 2176*256 */
#define NG      64
#define TT      512
#define OUTF    24

__device__ __forceinline__ float lrelu(float x){ return x > 0.f ? x : 0.2f*x; }
__device__ __forceinline__ float eluf (float x){ return x > 0.f ? x : __expf(x)-1.f; }
__device__ __forceinline__ float sigmf(float x){ return 1.f/(1.f+__expf(-x)); }
__device__ __forceinline__ float tanhfast(float x){ return 1.f - 2.f/(__expf(2.f*x)+1.f); }
__device__ __forceinline__ float bcast(float v, int k){
  return __int_as_float(__builtin_amdgcn_readlane(__float_as_int(v), k));
}

// ---------------- CSR build: incoming-edge lists per destination ----------------
__global__ __launch_bounds__(256) void k_deg(const int* __restrict__ ei,
                                             int* __restrict__ deg){
  int e = blockIdx.x*256 + threadIdx.x;   // e < NET
  int d = (e < NE) ? ei[NE+e] : (e - NE);
  atomicAdd(deg + d, 1);
}

__global__ __launch_bounds__(1024) void k_scan(const int* __restrict__ deg,
                                               int* __restrict__ rowptr){
  __shared__ int ps[1024];
  const int t = threadIdx.x;
  const int base = t*32;
  int local[32]; int s = 0;
  #pragma unroll
  for(int i=0;i<32;i++){ local[i]=deg[base+i]; s+=local[i]; }
  ps[t]=s; __syncthreads();
  for(int off=1; off<1024; off<<=1){
    int v = (t>=off) ? ps[t-off] : 0;
    __syncthreads();
    ps[t]+=v;
    __syncthreads();
  }
  int run = (t==0) ? 0 : ps[t-1];
  #pragma unroll
  for(int i=0;i<32;i++){ rowptr[base+i]=run; run+=local[i]; }
  if(t==1023) rowptr[N_NODES]=run;
}

__global__ __launch_bounds__(256) void k_fill(const int* __restrict__ ei,
                                              const int* __restrict__ rowptr,
                                              int* __restrict__ cur,
                                              int* __restrict__ col){
  int e = blockIdx.x*256 + threadIdx.x;   // e < NET
  int s, d;
  if(e < NE){ s = ei[e]; d = ei[NE+e]; } else { s = e-NE; d = s; }
  int pos = atomicAdd(cur + d, 1);
  col[rowptr[d] + pos] = s;
}

// ---------------- GAT layer 1, restructured (h1 never materialized) ----------------
__global__ __launch_bounds__(256) void k_alpha1x(const float* __restrict__ x,
                                                 const float* __restrict__ W1,
                                                 const float* __restrict__ a_src,
                                                 const float* __restrict__ a_dst,
                                                 float* __restrict__ as1,
                                                 float* __restrict__ ad1){
  __shared__ float ps[256];
  const int tid = threadIdx.x;
  {
    const int k = tid>>3, q = tid&7;
    const int h = q>>1, isd = q&1;
    const float* av = (isd ? a_dst : a_src) + h*64;
    const float* wr = W1 + k*256 + h*64;
    float acc = 0.f;
    #pragma unroll
    for(int c=0;c<64;c++) acc += wr[c]*av[c];
    ps[(isd?128:0) + k*4 + h] = acc;
  }
  __syncthreads();
  const int n = blockIdx.x*256 + tid;
  const float4* xr = (const float4*)(x + n*32);
  float sa0=0.f,sa1=0.f,sa2=0.f,sa3=0.f, sd0=0.f,sd1=0.f,sd2=0.f,sd3=0.f;
  #pragma unroll
  for(int k4=0;k4<8;k4++){
    float4 v = xr[k4];
    const float* pa = ps + (4*k4)*4;
    const float* pd = ps + 128 + (4*k4)*4;
    sa0 += v.x*pa[0] + v.y*pa[4] + v.z*pa[8]  + v.w*pa[12];
    sa1 += v.x*pa[1] + v.y*pa[5] + v.z*pa[9]  + v.w*pa[13];
    sa2 += v.x*pa[2] + v.y*pa[6] + v.z*pa[10] + v.w*pa[14];
    sa3 += v.x*pa[3] + v.y*pa[7] + v.z*pa[11] + v.w*pa[15];
    sd0 += v.x*pd[0] + v.y*pd[4] + v.z*pd[8]  + v.w*pd[12];
    sd1 += v.x*pd[1] + v.y*pd[5] + v.z*pd[9]  + v.w*pd[13];
    sd2 += v.x*pd[2] + v.y*pd[6] + v.z*pd[10] + v.w*pd[14];
    sd3 += v.x*pd[3] + v.y*pd[7] + v.z*pd[11] + v.w*pd[15];
  }
  *(float4*)(as1+n*4) = make_float4(sa0,sa1,sa2,sa3);
  *(float4*)(ad1+n*4) = make_float4(sd0,sd1,sd2,sd3);
}

// aggregate x per (node, head): agg[d,h,k] = sum_e w_e^h x[src_e,k]; s14 = sum w.
__global__ __launch_bounds__(256) void k_gatx(const int* __restrict__ rowptr,
                                              const int* __restrict__ col,
                                              const float* __restrict__ as1,
                                              const float* __restrict__ ad1,
                                              const float* __restrict__ x,
                                              float* __restrict__ agg,
                                              float* __restrict__ s14){
  const int node = blockIdx.x*4 + (threadIdx.x>>6);
  const int lane = threadIdx.x & 63;
  const int h0   = lane>>5;                  // 0 or 1
  const int c    = lane & 31;
  const int beg = rowptr[node], end = rowptr[node+1];
  const float adA = ad1[node*4 + h0];
  const float adB = ad1[node*4 + h0 + 2];
  float accA=0.f, accB=0.f, wsA=0.f, wsB=0.f;
  int j = beg;
  for(; j+3 < end; j += 4){
    int s0 = col[j], s1 = col[j+1], s2 = col[j+2], s3 = col[j+3];
    float4 q0 = *(const float4*)(as1 + s0*4);
    float4 q1 = *(const float4*)(as1 + s1*4);
    float4 q2 = *(const float4*)(as1 + s2*4);
    float4 q3 = *(const float4*)(as1 + s3*4);
    float x0 = x[s0*32 + c];
    float x1 = x[s1*32 + c];
    float x2 = x[s2*32 + c];
    float x3 = x[s3*32 + c];
    float wA0 = __expf(lrelu((h0?q0.y:q0.x) + adA));
    float wA1 = __expf(lrelu((h0?q1.y:q1.x) + adA));
    float wA2 = __expf(lrelu((h0?q2.y:q2.x) + adA));
    float wA3 = __expf(lrelu((h0?q3.y:q3.x) + adA));
    float wB0 = __expf(lrelu((h0?q0.w:q0.z) + adB));
    float wB1 = __expf(lrelu((h0?q1.w:q1.z) + adB));
    float wB2 = __expf(lrelu((h0?q2.w:q2.z) + adB));
    float wB3 = __expf(lrelu((h0?q3.w:q3.z) + adB));
    accA += wA0*x0 + wA1*x1 + wA2*x2 + wA3*x3;
    accB += wB0*x0 + wB1*x1 + wB2*x2 + wB3*x3;
    wsA  += (wA0+wA1) + (wA2+wA3);
    wsB  += (wB0+wB1) + (wB2+wB3);
  }
  for(; j < end; j++){
    int s0 = col[j];
    float4 q0 = *(const float4*)(as1 + s0*4);
    float wA0 = __expf(lrelu((h0?q0.y:q0.x) + adA));
    float wB0 = __expf(lrelu((h0?q0.w:q0.z) + adB));
    float x0 = x[s0*32 + c];
    accA += wA0*x0; accB += wB0*x0;
    wsA += wA0; wsB += wB0;
  }
  agg[node*128 + h0*32 + c]     = accA;
  agg[node*128 + (h0+2)*32 + c] = accB;
  if(c == 0){
    s14[node*4 + h0]     = wsA;
    s14[node*4 + h0 + 2] = wsB;
  }
}

// Fused: out1 = ELU(agg@W1/s + b1) [LDS only] ; h2 = out1@W2 ; as2/ad2 from h2.
__global__ __launch_bounds__(256) void k_g12(const float* __restrict__ agg,
                                             const float* __restrict__ W1,
                                             const float* __restrict__ s14,
                                             const float* __restrict__ b1,
                                             const float* __restrict__ W2,
                                             const float* __restrict__ a_src2,
                                             const float* __restrict__ a_dst2,
                                             float* __restrict__ h2,
                                             float* __restrict__ as2,
                                             float* __restrict__ ad2){
  __shared__ __align__(16) float ags[32*128];   // 16KB; reused as h2 tile
  __shared__ __align__(16) float o1s[32*256];   // 32KB
  __shared__ float sv[128];
  const int tid  = threadIdx.x;
  const int row0 = blockIdx.x*32;
  const float4* ag = (const float4*)(agg + (size_t)row0*128);
  float4* a4 = (float4*)ags;
  for(int i=tid;i<1024;i+=256) a4[i]=ag[i];
  if(tid<32) ((float4*)sv)[tid]=((const float4*)(s14+row0*4))[tid];
  float wc[32];
  #pragma unroll
  for(int k=0;k<32;k++) wc[k]=W1[k*256+tid];
  const float bb=b1[tid];
  __syncthreads();
  const int h = tid>>6;
  for(int r=0;r<32;r++){
    const float4* ar=(const float4*)(ags + r*128 + h*32);
    float acc=0.f;
    #pragma unroll
    for(int k4=0;k4<8;k4++){
      float4 v=ar[k4];
      acc += v.x*wc[4*k4]+v.y*wc[4*k4+1]+v.z*wc[4*k4+2]+v.w*wc[4*k4+3];
    }
    float inv = 1.f/(sv[r*4+h] + 1e-16f);
    o1s[r*256+tid] = eluf(acc*inv + bb);
  }
  __syncthreads();
  const int c0=(tid&15)*4;
  const int r0=(tid>>4)*2;
  float acc2[2][4]={};
  for(int k=0;k<256;k+=4){
    float wv[4][4];
    #pragma unroll
    for(int i=0;i<4;i++){
      float4 w=*(const float4*)(W2+(k+i)*64+c0);
      wv[i][0]=w.x; wv[i][1]=w.y; wv[i][2]=w.z; wv[i][3]=w.w;
    }
    #pragma unroll
    for(int i=0;i<2;i++){
      float4 xv=*(const float4*)(o1s+(r0+i)*256+k);
      #pragma unroll
      for(int j=0;j<4;j++)
        acc2[i][j]+=xv.x*wv[0][j]+xv.y*wv[1][j]+xv.z*wv[2][j]+xv.w*wv[3][j];
    }
  }
  float* h2s = ags;
  #pragma unroll
  for(int i=0;i<2;i++){
    float4 o = make_float4(acc2[i][0],acc2[i][1],acc2[i][2],acc2[i][3]);
    *(float4*)(h2 + (size_t)(row0+r0+i)*64 + c0) = o;
    *(float4*)(h2s + (r0+i)*64 + c0) = o;
  }
  __syncthreads();
  if(tid < 32){
    const float4* hp=(const float4*)(h2s + tid*64);
    float sa=0.f, sd=0.f;
    #pragma unroll
    for(int i=0;i<16;i++){
      float4 v=hp[i];
      float4 a=((const float4*)a_src2)[i];
      float4 d=((const float4*)a_dst2)[i];
      sa+=v.x*a.x+v.y*a.y+v.z*a.z+v.w*a.w;
      sd+=v.x*d.x+v.y*d.y+v.z*d.z+v.w*d.w;
    }
    as2[row0+tid]=sa; ad2[row0+tid]=sd;
  }
}

// fused gather layer 2: one wave per node, lane = channel; 4-wide unrolled.
__global__ __launch_bounds__(256) void k_gat2(const int* __restrict__ rowptr,
                                              const int* __restrict__ col,
                                              const float* __restrict__ as2,
                                              const float* __restrict__ ad2,
                                              const float* __restrict__ h2,
                                              const float* __restrict__ b2,
                                              float* __restrict__ out2){
  const int node = blockIdx.x*4 + (threadIdx.x>>6);
  const int lane = threadIdx.x & 63;
  const int beg = rowptr[node], end = rowptr[node+1];
  const float ad = ad2[node];
  float acc = 0.f, s = 0.f;
  int j = beg;
  for(; j+3 < end; j += 4){
    int s0 = col[j], s1 = col[j+1], s2 = col[j+2], s3 = col[j+3];
    float a0 = as2[s0], a1 = as2[s1], a2 = as2[s2], a3 = as2[s3];
    float v0 = h2[s0*64+lane], v1 = h2[s1*64+lane];
    float v2 = h2[s2*64+lane], v3 = h2[s3*64+lane];
    float w0 = __expf(lrelu(a0 + ad));
    float w1 = __expf(lrelu(a1 + ad));
    float w2 = __expf(lrelu(a2 + ad));
    float w3 = __expf(lrelu(a3 + ad));
    acc += w0*v0 + w1*v1 + w2*v2 + w3*v3;
    s += (w0+w1) + (w2+w3);
  }
  for(; j < end; j++){
    int s0 = col[j];
    float w0 = __expf(lrelu(as2[s0] + ad));
    acc += w0*h2[s0*64+lane];
    s += w0;
  }
  const float inv = 1.f/(s + 1e-16f);
  out2[node*64+lane] = eluf(acc*inv + b2[lane]);
}

// ---------------- GRU: gi1 = in @ Wih0^T + bih0   [N,64]@[64,192] ----------------
__global__ __launch_bounds__(256) void k_gemm_gi(const float* __restrict__ in,
                                                 const float* __restrict__ Wih,
                                                 const float* __restrict__ bih,
                                                 float* __restrict__ gi){
  __shared__ __align__(16) float xs[64*64];
  __shared__ float wT[64*192];
  const int tid=threadIdx.x;
  const int row0=blockIdx.x*64;
  const float4* xg=(const float4*)(in+row0*64);
  float4* xs4=(float4*)xs;
  for(int i=tid;i<1024;i+=256) xs4[i]=xg[i];
  for(int i=tid;i<12288;i+=256){ wT[(i&63)*192+(i>>6)] = Wih[i]; }
  __syncthreads();
  if(tid<192){
    float wr[64];
    #pragma unroll
    for(int k=0;k<64;k++) wr[k]=wT[k*192+tid];
    const float bj=bih[tid];
    for(int r=0;r<64;r++){
      float acc=bj;
      const float4* xr=(const float4*)(xs+r*64);
      #pragma unroll
      for(int k4=0;k4<16;k4++){
        float4 v=xr[k4];
        acc+=v.x*wr[4*k4]+v.y*wr[4*k4+1]+v.z*wr[4*k4+2]+v.w*wr[4*k4+3];
      }
      gi[(row0+r)*192+tid]=acc;
    }
  }
}

// Fused 2-layer GRU — r8's k_gruR VERBATIM (best measured across 9 designs: 443us).
__global__ __launch_bounds__(576,3) void k_gruR(const float* __restrict__ gi1,
                                                const float* __restrict__ Whh0,
                                                const float* __restrict__ bhh0,
                                                const float* __restrict__ Wih1,
                                                const float* __restrict__ bih1,
                                                const float* __restrict__ Whh1,
                                                const float* __restrict__ bhh1,
                                                const float* __restrict__ Wl,
                                                const float* __restrict__ bl,
                                                float* __restrict__ fout){
  __shared__ float h1s[64];
  __shared__ float h2s[64];
  __shared__ float gh1s[192];
  __shared__ float gi2s[192];
  __shared__ float gh2s[192];
  __shared__ float g1r[2][192];   // gi1 ring (parity)
  const int tid  = threadIdx.x;
  const int w    = tid >> 6;
  const int lane = tid & 63;
  const int b    = blockIdx.x;
  const float* gib = gi1 + (size_t)b*TT*192;

  const int crew = w/3;                     // wave-uniform
  const int row  = (w%3)*64 + lane;
  const float* W  = (crew==0) ? Whh0 : (crew==1) ? Wih1 : Whh1;
  const float* bb = (crew==0) ? bhh0 : (crew==1) ? bih1 : bhh1;
  float* dst      = (crew==0) ? gh1s : (crew==1) ? gi2s : gh2s;

  const float4* wp = (const float4*)(W + row*64);
  float4 Wv0=wp[0],  Wv1=wp[1],  Wv2=wp[2],  Wv3=wp[3];
  float4 Wv4=wp[4],  Wv5=wp[5],  Wv6=wp[6],  Wv7=wp[7];
  float4 Wv8=wp[8],  Wv9=wp[9],  WvA=wp[10], WvB=wp[11];
  float4 WvC=wp[12], WvD=wp[13], WvE=wp[14], WvF=wp[15];
  const float bias = bb[row];

  float giv = 0.f;
  if(w < 3){                                // crew0: prefill ring step 0, reg step 1
    g1r[0][row] = gib[row];
    giv = gib[192 + row];
  }
  if(tid < 64){ h1s[tid]=0.f; h2s[tid]=0.f; }
  __syncthreads();

  for(int i=0;i<=TT;i++){
    // ---- phase A ----
    float hv = (crew==2) ? h2s[lane] : h1s[lane];
    if(w < 3){
      int pst = i+1;
      if(pst < TT) g1r[pst&1][row] = giv;   // value loaded last iter (latency hidden)
      int nst = i+2;
      if(nst < TT) giv = gib[nst*192 + row];
    }
    float a0=bias, a1=0.f, a2=0.f, a3=0.f;
#define DOT4(WV, BASE) \
    a0 = fmaf(bcast(hv, BASE+0), WV.x, a0); \
    a1 = fmaf(bcast(hv, BASE+1), WV.y, a1); \
    a2 = fmaf(bcast(hv, BASE+2), WV.z, a2); \
    a3 = fmaf(bcast(hv, BASE+3), WV.w, a3);
    DOT4(Wv0, 0)  DOT4(Wv1, 4)  DOT4(Wv2, 8)  DOT4(Wv3, 12)
    DOT4(Wv4, 16) DOT4(Wv5, 20) DOT4(Wv6, 24) DOT4(Wv7, 28)
    DOT4(Wv8, 32) DOT4(Wv9, 36) DOT4(WvA, 40) DOT4(WvB, 44)
    DOT4(WvC, 48) DOT4(WvD, 52) DOT4(WvE, 56) DOT4(WvF, 60)
#undef DOT4
    dst[row] = (a0+a1)+(a2+a3);
    __syncthreads();
    // ---- phase B: gate updates (guards define the skew) ----
    if(w == 0){
      if(i < TT){
        float r = sigmf(g1r[i&1][lane]     + gh1s[lane]);
        float z = sigmf(g1r[i&1][64+lane]  + gh1s[64+lane]);
        float n = tanhfast(g1r[i&1][128+lane] + r*gh1s[128+lane]);
        h1s[lane] = (1.f-z)*n + z*h1s[lane];
      }
    } else if(w == 3){
      if(i >= 1){
        float r = sigmf(gi2s[lane]     + gh2s[lane]);
        float z = sigmf(gi2s[64+lane]  + gh2s[64+lane]);
        float n = tanhfast(gi2s[128+lane] + r*gh2s[128+lane]);
        h2s[lane] = (1.f-z)*n + z*h2s[lane];
      }
    }
    __syncthreads();
  }

  if(tid < 24){
    float acc = bl[tid];
    const float4* wl4 = (const float4*)(Wl + tid*64);
    #pragma unroll
    for(int k4=0;k4<16;k4++){
      float4 h4 = *(const float4*)(h2s + 4*k4);
      float4 w4 = wl4[k4];
      acc += h4.x*w4.x + h4.y*w4.y + h4.z*w4.z + h4.w*w4.w;
    }
    fout[b*24+tid] = acc;
  }
}

extern "C" void kernel_launch(void* const* d_in, const int* in_sizes, int n_in,
                              void* d_out, int out_size, void* d_ws, size_t ws_size,
                              hipStream_t stream){
  const float* x     =(const float*)d_in[0];
  const int*   ei    =(const int*  )d_in[1];
  const float* W1    =(const float*)d_in[3];
  const float* a_src1=(const float*)d_in[4];
  const float* a_dst1=(const float*)d_in[5];
  const float* b1    =(const float*)d_in[6];
  const float* W2    =(const float*)d_in[7];
  const float* a_src2=(const float*)d_in[8];
  const float* a_dst2=(const float*)d_in[9];
  const float* b2    =(const float*)d_in[10];
  const float* Wih0  =(const float*)d_in[11];
  const float* Whh0  =(const float*)d_in[12];
  const float* bih0  =(const float*)d_in[13];
  const float* bhh0  =(const float*)d_in[14];
  const float* Wih1  =(const float*)d_in[15];
  const float* Whh1  =(const float*)d_in[16];
  const float* bih1  =(const float*)d_in[17];
  const float* bhh1  =(const float*)d_in[18];
  const float* Wl    =(const float*)d_in[19];
  const float* bl    =(const float*)d_in[20];

  float* ws   = (float*)d_ws;
  float* agg  = ws;                  // 4194304 [N,128] (dead after k_g12)
  float* s14  = ws + 4194304;        // 131072 [N,4]
  float* gi   = ws;                  // overwrites agg after it's dead
  float* out2 = ws + 8388608;        // 2097152 (k_gat2 output)
  float* h2   = ws + 16777216;       // 2097152
  float* as1  = ws + 18874368;       // 131072
  float* ad1  = as1 + 131072;        // 131072
  float* as2  = ad1 + 131072;        // 32768
  float* ad2  = as2 + 32768;         // 32768
  int* rowptr = (int*)(ad2 + 32768); // 32769 (padded to 32800)
  int* deg    = rowptr + 32800;      // 32768
  int* cur    = deg + 32768;         // 32768 (contiguous with deg: one memset)
  int* col    = cur + 32768;         // 557056
  float* fo   = (float*)d_out;

  hipMemsetAsync(deg, 0, 2*32768*sizeof(int), stream);  // deg + cur

  k_deg   <<<2176,256,0,stream>>>(ei,deg);
  k_scan  <<<1  ,1024,0,stream>>>(deg,rowptr);
  k_fill  <<<2176,256,0,stream>>>(ei,rowptr,cur,col);

  k_alpha1x<<<128 ,256,0,stream>>>(x,W1,a_src1,a_dst1,as1,ad1);
  k_gatx   <<<8192,256,0,stream>>>(rowptr,col,as1,ad1,x,agg,s14);
  k_g12    <<<1024,256,0,stream>>>(agg,W1,s14,b1,W2,a_src2,a_dst2,h2,as2,ad2);
  k_gat2   <<<8192,256,0,stream>>>(rowptr,col,as2,ad2,h2,b2,out2);
  k_gemm_gi<<<512 ,256,0,stream>>>(out2,Wih0,bih0,gi);
  k_gruR   <<<64  ,576,0,stream>>>(gi,Whh0,bhh0,Wih1,bih1,Whh1,bhh1,Wl,bl,fo);
  (void)in_sizes; (void)n_in; (void)out_size; (void)ws_size;
}

// Round 17
// 729.475 us; speedup vs baseline: 1.1495x; 1.0342x over previous
//
#include <hip/hip_runtime.h>
#include <hip/hip_bf16.h>

#define N_NODES 32768
#define F_IN    32
#define HC      64
#define HEADS   4
#define NE      524288
#define NET     (NE + N_NODES)   /* 557056 = 2176*256 */
#define NG      64
#define TT      512
#define OUTF    24

__device__ __forceinline__ float lrelu(float x){ return x > 0.f ? x : 0.2f*x; }
__device__ __forceinline__ float eluf (float x){ return x > 0.f ? x : __expf(x)-1.f; }
__device__ __forceinline__ float sigmf(float x){ return 1.f/(1.f+__expf(-x)); }
__device__ __forceinline__ float tanhfast(float x){ return 1.f - 2.f/(__expf(2.f*x)+1.f); }
__device__ __forceinline__ float bcast(float v, int k){
  return __int_as_float(__builtin_amdgcn_readlane(__float_as_int(v), k));
}

// ---------------- CSR build: incoming-edge lists per destination ----------------
__global__ __launch_bounds__(256) void k_deg(const int* __restrict__ ei,
                                             int* __restrict__ deg){
  int e = blockIdx.x*256 + threadIdx.x;   // e < NET
  int d = (e < NE) ? ei[NE+e] : (e - NE);
  atomicAdd(deg + d, 1);
}

__global__ __launch_bounds__(1024) void k_scan(const int* __restrict__ deg,
                                               int* __restrict__ rowptr){
  __shared__ int ps[1024];
  const int t = threadIdx.x;
  const int base = t*32;
  int local[32]; int s = 0;
  #pragma unroll
  for(int i=0;i<32;i++){ local[i]=deg[base+i]; s+=local[i]; }
  ps[t]=s; __syncthreads();
  for(int off=1; off<1024; off<<=1){
    int v = (t>=off) ? ps[t-off] : 0;
    __syncthreads();
    ps[t]+=v;
    __syncthreads();
  }
  int run = (t==0) ? 0 : ps[t-1];
  #pragma unroll
  for(int i=0;i<32;i++){ rowptr[base+i]=run; run+=local[i]; }
  if(t==1023) rowptr[N_NODES]=run;
}

__global__ __launch_bounds__(256) void k_fill(const int* __restrict__ ei,
                                              const int* __restrict__ rowptr,
                                              int* __restrict__ cur,
                                              int* __restrict__ col){
  int e = blockIdx.x*256 + threadIdx.x;   // e < NET
  int s, d;
  if(e < NE){ s = ei[e]; d = ei[NE+e]; } else { s = e-NE; d = s; }
  int pos = atomicAdd(cur + d, 1);
  col[rowptr[d] + pos] = s;
}

// ---------------- GAT layer 1, restructured (h1 never materialized) ----------------
__global__ __launch_bounds__(256) void k_alpha1x(const float* __restrict__ x,
                                                 const float* __restrict__ W1,
                                                 const float* __restrict__ a_src,
                                                 const float* __restrict__ a_dst,
                                                 float* __restrict__ as1,
                                                 float* __restrict__ ad1){
  __shared__ float ps[256];
  const int tid = threadIdx.x;
  {
    const int k = tid>>3, q = tid&7;
    const int h = q>>1, isd = q&1;
    const float* av = (isd ? a_dst : a_src) + h*64;
    const float* wr = W1 + k*256 + h*64;
    float acc = 0.f;
    #pragma unroll
    for(int c=0;c<64;c++) acc += wr[c]*av[c];
    ps[(isd?128:0) + k*4 + h] = acc;
  }
  __syncthreads();
  const int n = blockIdx.x*256 + tid;
  const float4* xr = (const float4*)(x + n*32);
  float sa0=0.f,sa1=0.f,sa2=0.f,sa3=0.f, sd0=0.f,sd1=0.f,sd2=0.f,sd3=0.f;
  #pragma unroll
  for(int k4=0;k4<8;k4++){
    float4 v = xr[k4];
    const float* pa = ps + (4*k4)*4;
    const float* pd = ps + 128 + (4*k4)*4;
    sa0 += v.x*pa[0] + v.y*pa[4] + v.z*pa[8]  + v.w*pa[12];
    sa1 += v.x*pa[1] + v.y*pa[5] + v.z*pa[9]  + v.w*pa[13];
    sa2 += v.x*pa[2] + v.y*pa[6] + v.z*pa[10] + v.w*pa[14];
    sa3 += v.x*pa[3] + v.y*pa[7] + v.z*pa[11] + v.w*pa[15];
    sd0 += v.x*pd[0] + v.y*pd[4] + v.z*pd[8]  + v.w*pd[12];
    sd1 += v.x*pd[1] + v.y*pd[5] + v.z*pd[9]  + v.w*pd[13];
    sd2 += v.x*pd[2] + v.y*pd[6] + v.z*pd[10] + v.w*pd[14];
    sd3 += v.x*pd[3] + v.y*pd[7] + v.z*pd[11] + v.w*pd[15];
  }
  *(float4*)(as1+n*4) = make_float4(sa0,sa1,sa2,sa3);
  *(float4*)(ad1+n*4) = make_float4(sd0,sd1,sd2,sd3);
}

// aggregate x per (node, head): agg[d,h,k] = sum_e w_e^h x[src_e,k]; s14 = sum w.
__global__ __launch_bounds__(256) void k_gatx(const int* __restrict__ rowptr,
                                              const int* __restrict__ col,
                                              const float* __restrict__ as1,
                                              const float* __restrict__ ad1,
                                              const float* __restrict__ x,
                                              float* __restrict__ agg,
                                              float* __restrict__ s14){
  const int node = blockIdx.x*4 + (threadIdx.x>>6);
  const int lane = threadIdx.x & 63;
  const int h0   = lane>>5;                  // 0 or 1
  const int c    = lane & 31;
  const int beg = rowptr[node], end = rowptr[node+1];
  const float adA = ad1[node*4 + h0];
  const float adB = ad1[node*4 + h0 + 2];
  float accA=0.f, accB=0.f, wsA=0.f, wsB=0.f;
  int j = beg;
  for(; j+3 < end; j += 4){
    int s0 = col[j], s1 = col[j+1], s2 = col[j+2], s3 = col[j+3];
    float4 q0 = *(const float4*)(as1 + s0*4);
    float4 q1 = *(const float4*)(as1 + s1*4);
    float4 q2 = *(const float4*)(as1 + s2*4);
    float4 q3 = *(const float4*)(as1 + s3*4);
    float x0 = x[s0*32 + c];
    float x1 = x[s1*32 + c];
    float x2 = x[s2*32 + c];
    float x3 = x[s3*32 + c];
    float wA0 = __expf(lrelu((h0?q0.y:q0.x) + adA));
    float wA1 = __expf(lrelu((h0?q1.y:q1.x) + adA));
    float wA2 = __expf(lrelu((h0?q2.y:q2.x) + adA));
    float wA3 = __expf(lrelu((h0?q3.y:q3.x) + adA));
    float wB0 = __expf(lrelu((h0?q0.w:q0.z) + adB));
    float wB1 = __expf(lrelu((h0?q1.w:q1.z) + adB));
    float wB2 = __expf(lrelu((h0?q2.w:q2.z) + adB));
    float wB3 = __expf(lrelu((h0?q3.w:q3.z) + adB));
    accA += wA0*x0 + wA1*x1 + wA2*x2 + wA3*x3;
    accB += wB0*x0 + wB1*x1 + wB2*x2 + wB3*x3;
    wsA  += (wA0+wA1) + (wA2+wA3);
    wsB  += (wB0+wB1) + (wB2+wB3);
  }
  for(; j < end; j++){
    int s0 = col[j];
    float4 q0 = *(const float4*)(as1 + s0*4);
    float wA0 = __expf(lrelu((h0?q0.y:q0.x) + adA));
    float wB0 = __expf(lrelu((h0?q0.w:q0.z) + adB));
    float x0 = x[s0*32 + c];
    accA += wA0*x0; accB += wB0*x0;
    wsA += wA0; wsB += wB0;
  }
  agg[node*128 + h0*32 + c]     = accA;
  agg[node*128 + (h0+2)*32 + c] = accB;
  if(c == 0){
    s14[node*4 + h0]     = wsA;
    s14[node*4 + h0 + 2] = wsB;
  }
}

// Fused: out1 = ELU(agg@W1/s + b1) [LDS only] ; h2 = out1@W2 ; as2/ad2 from h2.
__global__ __launch_bounds__(256) void k_g12(const float* __restrict__ agg,
                                             const float* __restrict__ W1,
                                             const float* __restrict__ s14,
                                             const float* __restrict__ b1,
                                             const float* __restrict__ W2,
                                             const float* __restrict__ a_src2,
                                             const float* __restrict__ a_dst2,
                                             float* __restrict__ h2,
                                             float* __restrict__ as2,
                                             float* __restrict__ ad2){
  __shared__ __align__(16) float ags[32*128];   // 16KB; reused as h2 tile
  __shared__ __align__(16) float o1s[32*256];   // 32KB
  __shared__ float sv[128];
  const int tid  = threadIdx.x;
  const int row0 = blockIdx.x*32;
  const float4* ag = (const float4*)(agg + (size_t)row0*128);
  float4* a4 = (float4*)ags;
  for(int i=tid;i<1024;i+=256) a4[i]=ag[i];
  if(tid<32) ((float4*)sv)[tid]=((const float4*)(s14+row0*4))[tid];
  float wc[32];
  #pragma unroll
  for(int k=0;k<32;k++) wc[k]=W1[k*256+tid];
  const float bb=b1[tid];
  __syncthreads();
  const int h = tid>>6;
  for(int r=0;r<32;r++){
    const float4* ar=(const float4*)(ags + r*128 + h*32);
    float acc=0.f;
    #pragma unroll
    for(int k4=0;k4<8;k4++){
      float4 v=ar[k4];
      acc += v.x*wc[4*k4]+v.y*wc[4*k4+1]+v.z*wc[4*k4+2]+v.w*wc[4*k4+3];
    }
    float inv = 1.f/(sv[r*4+h] + 1e-16f);
    o1s[r*256+tid] = eluf(acc*inv + bb);
  }
  __syncthreads();
  const int c0=(tid&15)*4;
  const int r0=(tid>>4)*2;
  float acc2[2][4]={};
  for(int k=0;k<256;k+=4){
    float wv[4][4];
    #pragma unroll
    for(int i=0;i<4;i++){
      float4 w=*(const float4*)(W2+(k+i)*64+c0);
      wv[i][0]=w.x; wv[i][1]=w.y; wv[i][2]=w.z; wv[i][3]=w.w;
    }
    #pragma unroll
    for(int i=0;i<2;i++){
      float4 xv=*(const float4*)(o1s+(r0+i)*256+k);
      #pragma unroll
      for(int j=0;j<4;j++)
        acc2[i][j]+=xv.x*wv[0][j]+xv.y*wv[1][j]+xv.z*wv[2][j]+xv.w*wv[3][j];
    }
  }
  float* h2s = ags;
  #pragma unroll
  for(int i=0;i<2;i++){
    float4 o = make_float4(acc2[i][0],acc2[i][1],acc2[i][2],acc2[i][3]);
    *(float4*)(h2 + (size_t)(row0+r0+i)*64 + c0) = o;
    *(float4*)(h2s + (r0+i)*64 + c0) = o;
  }
  __syncthreads();
  if(tid < 32){
    const float4* hp=(const float4*)(h2s + tid*64);
    float sa=0.f, sd=0.f;
    #pragma unroll
    for(int i=0;i<16;i++){
      float4 v=hp[i];
      float4 a=((const float4*)a_src2)[i];
      float4 d=((const float4*)a_dst2)[i];
      sa+=v.x*a.x+v.y*a.y+v.z*a.z+v.w*a.w;
      sd+=v.x*d.x+v.y*d.y+v.z*d.z+v.w*d.w;
    }
    as2[row0+tid]=sa; ad2[row0+tid]=sd;
  }
}

// fused gather layer 2: one wave per node, lane = channel; 4-wide unrolled.
__global__ __launch_bounds__(256) void k_gat2(const int* __restrict__ rowptr,
                                              const int* __restrict__ col,
                                              const float* __restrict__ as2,
                                              const float* __restrict__ ad2,
                                              const float* __restrict__ h2,
                                              const float* __restrict__ b2,
                                              float* __restrict__ out2){
  const int node = blockIdx.x*4 + (threadIdx.x>>6);
  const int lane = threadIdx.x & 63;
  const int beg = rowptr[node], end = rowptr[node+1];
  const float ad = ad2[node];
  float acc = 0.f, s = 0.f;
  int j = beg;
  for(; j+3 < end; j += 4){
    int s0 = col[j], s1 = col[j+1], s2 = col[j+2], s3 = col[j+3];
    float a0 = as2[s0], a1 = as2[s1], a2 = as2[s2], a3 = as2[s3];
    float v0 = h2[s0*64+lane], v1 = h2[s1*64+lane];
    float v2 = h2[s2*64+lane], v3 = h2[s3*64+lane];
    float w0 = __expf(lrelu(a0 + ad));
    float w1 = __expf(lrelu(a1 + ad));
    float w2 = __expf(lrelu(a2 + ad));
    float w3 = __expf(lrelu(a3 + ad));
    acc += w0*v0 + w1*v1 + w2*v2 + w3*v3;
    s += (w0+w1) + (w2+w3);
  }
  for(; j < end; j++){
    int s0 = col[j];
    float w0 = __expf(lrelu(as2[s0] + ad));
    acc += w0*h2[s0*64+lane];
    s += w0;
  }
  const float inv = 1.f/(s + 1e-16f);
  out2[node*64+lane] = eluf(acc*inv + b2[lane]);
}

// ---------------- GRU: gi1 = in @ Wih0^T + bih0   [N,64]@[64,192] ----------------
__global__ __launch_bounds__(256) void k_gemm_gi(const float* __restrict__ in,
                                                 const float* __restrict__ Wih,
                                                 const float* __restrict__ bih,
                                                 float* __restrict__ gi){
  __shared__ __align__(16) float xs[64*64];
  __shared__ float wT[64*192];
  const int tid=threadIdx.x;
  const int row0=blockIdx.x*64;
  const float4* xg=(const float4*)(in+row0*64);
  float4* xs4=(float4*)xs;
  for(int i=tid;i<1024;i+=256) xs4[i]=xg[i];
  for(int i=tid;i<12288;i+=256){ wT[(i&63)*192+(i>>6)] = Wih[i]; }
  __syncthreads();
  if(tid<192){
    float wr[64];
    #pragma unroll
    for(int k=0;k<64;k++) wr[k]=wT[k*192+tid];
    const float bj=bih[tid];
    for(int r=0;r<64;r++){
      float acc=bj;
      const float4* xr=(const float4*)(xs+r*64);
      #pragma unroll
      for(int k4=0;k4<16;k4++){
        float4 v=xr[k4];
        acc+=v.x*wr[4*k4]+v.y*wr[4*k4+1]+v.z*wr[4*k4+2]+v.w*wr[4*k4+3];
      }
      gi[(row0+r)*192+tid]=acc;
    }
  }
}

// Fused 2-layer GRU, 3 waves/block (r8 structure, readlane amortized 3x).
// wave0: gh1 = bhh0 + Whh0.h1 (rows lane,64+lane,128+lane) + gi1 staging + h1 gate
// wave1: gi2 = bih1 + Wih1.h1
// wave2: gh2 = bhh1 + Whh1.h2 + h2 gate
// Each bcast(hv,k) feeds 3 FMAs: 64 readlane + 192 fma = 256 instr/lane vs r8's
// 128 for 1/3 the rows; busiest-SIMD phase-A issue 768 -> 512 cyc, 3-wave
// barriers. Skew/prefetch/DOT4 body identical to r8 (absmax-0 verified).
__global__ __launch_bounds__(192,1) void k_gru3(const float* __restrict__ gi1,
                                                const float* __restrict__ Whh0,
                                                const float* __restrict__ bhh0,
                                                const float* __restrict__ Wih1,
                                                const float* __restrict__ bih1,
                                                const float* __restrict__ Whh1,
                                                const float* __restrict__ bhh1,
                                                const float* __restrict__ Wl,
                                                const float* __restrict__ bl,
                                                float* __restrict__ fout){
  __shared__ float h1s[64];
  __shared__ float h2s[64];
  __shared__ float gh1s[192];
  __shared__ float gi2s[192];
  __shared__ float gh2s[192];
  __shared__ float g1r[2][192];   // gi1 ring (parity)
  const int tid  = threadIdx.x;
  const int w    = tid >> 6;
  const int lane = tid & 63;
  const int b    = blockIdx.x;
  const float* gib = gi1 + (size_t)b*TT*192;

  const float* W  = (w==0) ? Whh0 : (w==1) ? Wih1 : Whh1;
  const float* bb = (w==0) ? bhh0 : (w==1) ? bih1 : bhh1;
  float* dst      = (w==0) ? gh1s : (w==1) ? gi2s : gh2s;

  const float4* pa = (const float4*)(W + lane*64);
  const float4* pb = (const float4*)(W + (64+lane)*64);
  const float4* pc = (const float4*)(W + (128+lane)*64);
  float4 Av0=pa[0],  Av1=pa[1],  Av2=pa[2],  Av3=pa[3];
  float4 Av4=pa[4],  Av5=pa[5],  Av6=pa[6],  Av7=pa[7];
  float4 Av8=pa[8],  Av9=pa[9],  AvA=pa[10], AvB=pa[11];
  float4 AvC=pa[12], AvD=pa[13], AvE=pa[14], AvF=pa[15];
  float4 Bv0=pb[0],  Bv1=pb[1],  Bv2=pb[2],  Bv3=pb[3];
  float4 Bv4=pb[4],  Bv5=pb[5],  Bv6=pb[6],  Bv7=pb[7];
  float4 Bv8=pb[8],  Bv9=pb[9],  BvA=pb[10], BvB=pb[11];
  float4 BvC=pb[12], BvD=pb[13], BvE=pb[14], BvF=pb[15];
  float4 Cv0=pc[0],  Cv1=pc[1],  Cv2=pc[2],  Cv3=pc[3];
  float4 Cv4=pc[4],  Cv5=pc[5],  Cv6=pc[6],  Cv7=pc[7];
  float4 Cv8=pc[8],  Cv9=pc[9],  CvA=pc[10], CvB=pc[11];
  float4 CvC=pc[12], CvD=pc[13], CvE=pc[14], CvF=pc[15];
  const float biasA = bb[lane];
  const float biasB = bb[64+lane];
  const float biasC = bb[128+lane];

  float giv0 = 0.f, giv1 = 0.f, giv2 = 0.f;
  if(w == 0){                               // ring prefill: step 0 -> slot 0; regs = step 1
    g1r[0][lane]     = gib[lane];
    g1r[0][64+lane]  = gib[64+lane];
    g1r[0][128+lane] = gib[128+lane];
    giv0 = gib[192 + lane];
    giv1 = gib[192 + 64+lane];
    giv2 = gib[192 + 128+lane];
  }
  if(tid < 64){ h1s[tid]=0.f; h2s[tid]=0.f; }
  __syncthreads();

  for(int i=0;i<=TT;i++){
    // ---- phase A ----
    float hv = (w==2) ? h2s[lane] : h1s[lane];
    if(w == 0){
      int pst = i+1;
      if(pst < TT){
        g1r[pst&1][lane]     = giv0;
        g1r[pst&1][64+lane]  = giv1;
        g1r[pst&1][128+lane] = giv2;
      }
      int nst = i+2;
      if(nst < TT){
        giv0 = gib[(size_t)nst*192 + lane];
        giv1 = gib[(size_t)nst*192 + 64+lane];
        giv2 = gib[(size_t)nst*192 + 128+lane];
      }
    }
    float a0=biasA, a1=0.f, a2=0.f, a3=0.f;
    float b0=biasB, b1_=0.f, b2_=0.f, b3=0.f;
    float c0=biasC, c1=0.f, c2=0.f, c3=0.f;
#define DOT4(WA, WB, WC, BASE) { \
    float t0=bcast(hv,BASE+0), t1=bcast(hv,BASE+1), t2=bcast(hv,BASE+2), t3=bcast(hv,BASE+3); \
    a0 = fmaf(t0, WA.x, a0);  b0  = fmaf(t0, WB.x, b0);  c0 = fmaf(t0, WC.x, c0); \
    a1 = fmaf(t1, WA.y, a1);  b1_ = fmaf(t1, WB.y, b1_); c1 = fmaf(t1, WC.y, c1); \
    a2 = fmaf(t2, WA.z, a2);  b2_ = fmaf(t2, WB.z, b2_); c2 = fmaf(t2, WC.z, c2); \
    a3 = fmaf(t3, WA.w, a3);  b3  = fmaf(t3, WB.w, b3);  c3 = fmaf(t3, WC.w, c3); }
    DOT4(Av0,Bv0,Cv0, 0)  DOT4(Av1,Bv1,Cv1, 4)  DOT4(Av2,Bv2,Cv2, 8)  DOT4(Av3,Bv3,Cv3, 12)
    DOT4(Av4,Bv4,Cv4, 16) DOT4(Av5,Bv5,Cv5, 20) DOT4(Av6,Bv6,Cv6, 24) DOT4(Av7,Bv7,Cv7, 28)
    DOT4(Av8,Bv8,Cv8, 32) DOT4(Av9,Bv9,Cv9, 36) DOT4(AvA,BvA,CvA, 40) DOT4(AvB,BvB,CvB, 44)
    DOT4(AvC,BvC,CvC, 48) DOT4(AvD,BvD,CvD, 52) DOT4(AvE,BvE,CvE, 56) DOT4(AvF,BvF,CvF, 60)
#undef DOT4
    dst[lane]     = (a0+a1)+(a2+a3);
    dst[64+lane]  = (b0+b1_)+(b2_+b3);
    dst[128+lane] = (c0+c1)+(c2+c3);
    __syncthreads();
    // ---- phase B: gate updates (guards define the skew) ----
    if(w == 0){
      if(i < TT){
        float r = sigmf(g1r[i&1][lane]     + gh1s[lane]);
        float z = sigmf(g1r[i&1][64+lane]  + gh1s[64+lane]);
        float n = tanhfast(g1r[i&1][128+lane] + r*gh1s[128+lane]);
        h1s[lane] = (1.f-z)*n + z*h1s[lane];
      }
    } else if(w == 2){
      if(i >= 1){
        float r = sigmf(gi2s[lane]     + gh2s[lane]);
        float z = sigmf(gi2s[64+lane]  + gh2s[64+lane]);
        float n = tanhfast(gi2s[128+lane] + r*gh2s[128+lane]);
        h2s[lane] = (1.f-z)*n + z*h2s[lane];
      }
    }
    __syncthreads();
  }

  if(tid < 24){
    float acc = bl[tid];
    const float4* wl4 = (const float4*)(Wl + tid*64);
    #pragma unroll
    for(int k4=0;k4<16;k4++){
      float4 h4 = *(const float4*)(h2s + 4*k4);
      float4 w4 = wl4[k4];
      acc += h4.x*w4.x + h4.y*w4.y + h4.z*w4.z + h4.w*w4.w;
    }
    fout[b*24+tid] = acc;
  }
}

extern "C" void kernel_launch(void* const* d_in, const int* in_sizes, int n_in,
                              void* d_out, int out_size, void* d_ws, size_t ws_size,
                              hipStream_t stream){
  const float* x     =(const float*)d_in[0];
  const int*   ei    =(const int*  )d_in[1];
  const float* W1    =(const float*)d_in[3];
  const float* a_src1=(const float*)d_in[4];
  const float* a_dst1=(const float*)d_in[5];
  const float* b1    =(const float*)d_in[6];
  const float* W2    =(const float*)d_in[7];
  const float* a_src2=(const float*)d_in[8];
  const float* a_dst2=(const float*)d_in[9];
  const float* b2    =(const float*)d_in[10];
  const float* Wih0  =(const float*)d_in[11];
  const float* Whh0  =(const float*)d_in[12];
  const float* bih0  =(const float*)d_in[13];
  const float* bhh0  =(const float*)d_in[14];
  const float* Wih1  =(const float*)d_in[15];
  const float* Whh1  =(const float*)d_in[16];
  const float* bih1  =(const float*)d_in[17];
  const float* bhh1  =(const float*)d_in[18];
  const float* Wl    =(const float*)d_in[19];
  const float* bl    =(const float*)d_in[20];

  float* ws   = (float*)d_ws;
  float* agg  = ws;                  // 4194304 [N,128] (dead after k_g12)
  float* s14  = ws + 4194304;        // 131072 [N,4]
  float* gi   = ws;                  // overwrites agg after it's dead
  float* out2 = ws + 8388608;        // 2097152 (k_gat2 output)
  float* h2   = ws + 16777216;       // 2097152
  float* as1  = ws + 18874368;       // 131072
  float* ad1  = as1 + 131072;        // 131072
  float* as2  = ad1 + 131072;        // 32768
  float* ad2  = as2 + 32768;         // 32768
  int* rowptr = (int*)(ad2 + 32768); // 32769 (padded to 32800)
  int* deg    = rowptr + 32800;      // 32768
  int* cur    = deg + 32768;         // 32768 (contiguous with deg: one memset)
  int* col    = cur + 32768;         // 557056
  float* fo   = (float*)d_out;

  hipMemsetAsync(deg, 0, 2*32768*sizeof(int), stream);  // deg + cur

  k_deg   <<<2176,256,0,stream>>>(ei,deg);
  k_scan  <<<1  ,1024,0,stream>>>(deg,rowptr);
  k_fill  <<<2176,256,0,stream>>>(ei,rowptr,cur,col);

  k_alpha1x<<<128 ,256,0,stream>>>(x,W1,a_src1,a_dst1,as1,ad1);
  k_gatx   <<<8192,256,0,stream>>>(rowptr,col,as1,ad1,x,agg,s14);
  k_g12    <<<1024,256,0,stream>>>(agg,W1,s14,b1,W2,a_src2,a_dst2,h2,as2,ad2);
  k_gat2   <<<8192,256,0,stream>>>(rowptr,col,as2,ad2,h2,b2,out2);
  k_gemm_gi<<<512 ,256,0,stream>>>(out2,Wih0,bih0,gi);
  k_gru3   <<<64  ,192,0,stream>>>(gi,Whh0,bhh0,Wih1,bih1,Whh1,bhh1,Wl,bl,fo);
  (void)in_sizes; (void)n_in; (void)out_size; (void)ws_size;
}